// Round 10
// baseline (843.585 us; speedup 1.0000x reference)
//
#include <hip/hip_runtime.h>
#include <hip/hip_bf16.h>

// ---------------- problem constants ----------------
#define N_IN    32768
#define K_EMB   4096
#define D_EMB   256
#define ND      (N_IN * (size_t)D_EMB)          // 8388608
#define NK      ((size_t)N_IN * K_EMB)          // 134217728
// d_out layout (floats): [0]=loss, [1..1+ND)=quantized_st, [1+ND]=perplexity, [2+ND..)=encodings
#define OUT_PERP_OFF  (1 + ND)                  // 8388609
#define OUT_ENC_OFF   (2 + ND)                  // 8388610

#define W_SCALE 4096.0f

// ---------------- small ws layout (bytes) ----------------
#define WS_SUMB2   0          // 4096 f
#define WS_COUNTS  16384      // 4096 i
#define WS_LOSS    32768      // 1 f
#define WS_IDX     36864      // 32768 i

typedef _Float16 f16x8 __attribute__((ext_vector_type(8)));
typedef float    f32x4 __attribute__((ext_vector_type(4)));

__device__ __forceinline__ void gload_lds16(const void* g, void* l) {
    __builtin_amdgcn_global_load_lds(
        (const __attribute__((address_space(1))) unsigned int*)g,
        (__attribute__((address_space(3))) unsigned int*)l, 16, 0, 0);
}

__device__ __forceinline__ ushort h_bits(_Float16 h) {
    union { _Float16 h; ushort u; } cv; cv.h = h; return cv.u;
}
__device__ __forceinline__ float h_val(ushort u) {
    union { ushort u; _Float16 h; } cv; cv.u = u; return (float)cv.h;
}

// ---------------- k0: w -> fp16(w*4096), layout [c][256] ----------------
__global__ void vq_convw(const float* __restrict__ w, ushort* __restrict__ B) {
    int f = blockIdx.x * 256 + threadIdx.x;    // 0..262143 float4s
    float4 v = ((const float4*)w)[f];
    ushort4 s;
    s.x = h_bits((_Float16)(v.x * W_SCALE));
    s.y = h_bits((_Float16)(v.y * W_SCALE));
    s.z = h_bits((_Float16)(v.z * W_SCALE));
    s.w = h_bits((_Float16)(v.w * W_SCALE));
    ((ushort4*)B)[f] = s;
}

// ---------------- k1: sum of squares of the STORED fp16 codewords ----------------
__global__ void vq_sumb2(const ushort* __restrict__ B, float* __restrict__ sumb2) {
    int lane = threadIdx.x & 63;
    int row  = blockIdx.x * 4 + (threadIdx.x >> 6);
    ushort4 v = ((const ushort4*)B)[(size_t)row * 64 + lane];
    float a = h_val(v.x), b = h_val(v.y), c = h_val(v.z), d = h_val(v.w);
    float s = a * a + b * b + c * c + d * d;
    #pragma unroll
    for (int off = 32; off; off >>= 1) s += __shfl_down(s, off, 64);
    if (lane == 0) sumb2[row] = s;
}

// ---------------- k2: persistent fp16 MFMA GEMM + fused argmin (v2) ----------
// grid = 512 blocks (2/CU). Block: 256 thr (4 waves), 64 rows x ALL 4096 cols.
// Wave = 64 rows x 32-col slice of each 128-col chunk. K=256.
// LDS 64KB: A panel [64][256]f16 swizzled (32KB) | B dbuf 2x16KB (128cols x 64k).
// score(n,c) = sumb2[c] - 2*W_SCALE*dot(x16_n, w~_c)
__global__ __launch_bounds__(256, 2) void vq_gemm_argmin(
        const float* __restrict__ x, const ushort* __restrict__ Bw,
        const float* __restrict__ sumb2,
        int* __restrict__ indices, int* __restrict__ counts) {
    __shared__ __align__(16) char lds[65536];
    const int t = threadIdx.x;
    const int lane = t & 63;
    const int wx = t >> 6;                      // 0..3 col-slice
    const int rowBase = blockIdx.x * 64;
    const char* Bb = (const char*)Bw;

    // ---- prologue: A fp32->fp16 into LDS (swizzled) + first B chunk ----
    {
        const float4* gx = (const float4*)x;
        #pragma unroll
        for (int p = 0; p < 16; ++p) {
            int idx = p * 256 + t;              // float4 index in 64x64 panel
            int row = idx >> 6, k4 = idx & 63;
            float4 v = gx[(size_t)rowBase * 64 + idx];
            ushort4 h;
            h.x = h_bits((_Float16)v.x); h.y = h_bits((_Float16)v.y);
            h.z = h_bits((_Float16)v.z); h.w = h_bits((_Float16)v.w);
            int slot = (k4 >> 1) ^ (row & 7);   // 16B-slot XOR swizzle within row
            *(ushort4*)(lds + row * 512 + slot * 16 + (k4 & 1) * 8) = h;
        }
        #pragma unroll
        for (int p = 0; p < 4; ++p) {           // first B chunk (ct=0, ks=0)
            int o = p * 4096 + t * 16;
            int col = o >> 7;
            int ss = ((o & 127) >> 4) ^ (col & 7);
            gload_lds16(Bb + ((size_t)col * 256 + ss * 8) * 2, lds + 32768 + o);
        }
    }
    __syncthreads();

    f32x4 acc[4][2];
    float bv_[4][4]; int bi_[4][4];             // running best per [mf][r]
    #pragma unroll
    for (int i = 0; i < 4; ++i) {
        #pragma unroll
        for (int j = 0; j < 2; ++j) acc[i][j] = (f32x4)0.0f;
        #pragma unroll
        for (int r = 0; r < 4; ++r) { bv_[i][r] = 3.0e38f; bi_[i][r] = 0; }
    }

    #pragma unroll 4
    for (int u = 0; u < 128; ++u) {             // u = ct*4 + ks; chunk = 128c x 64k
        const int ks = u & 3, ct = u >> 2;
        const char* lb = lds + 32768 + (u & 1) * 16384;
        if (u < 127) {                          // prefetch next B chunk
            const int ctn = (u + 1) >> 2, ksn = (u + 1) & 3;
            char* lbn = lds + 32768 + ((u + 1) & 1) * 16384;
            #pragma unroll
            for (int p = 0; p < 4; ++p) {
                int o = p * 4096 + t * 16;
                int col = o >> 7;
                int ss = ((o & 127) >> 4) ^ (col & 7);
                gload_lds16(Bb + ((size_t)(ctn * 128 + col) * 256 + ksn * 64 + ss * 8) * 2,
                            lbn + o);
            }
        }
        __builtin_amdgcn_s_setprio(1);
        #pragma unroll
        for (int kk = 0; kk < 2; ++kk) {
            f16x8 av[4], bvv[2];
            #pragma unroll
            for (int mf = 0; mf < 4; ++mf) {
                int row = mf * 16 + (lane & 15);
                int slot = ks * 8 + ((kk * 4 + (lane >> 4)) ^ (row & 7));
                av[mf] = *(const f16x8*)(lds + row * 512 + slot * 16);
            }
            #pragma unroll
            for (int nf = 0; nf < 2; ++nf) {
                int col = wx * 32 + nf * 16 + (lane & 15);
                int slot = (kk * 4 + (lane >> 4)) ^ (col & 7);
                bvv[nf] = *(const f16x8*)(lb + col * 128 + slot * 16);
            }
            #pragma unroll
            for (int mf = 0; mf < 4; ++mf)
                #pragma unroll
                for (int nf = 0; nf < 2; ++nf)
                    acc[mf][nf] = __builtin_amdgcn_mfma_f32_16x16x32_f16(
                        av[mf], bvv[nf], acc[mf][nf], 0, 0, 0);
        }
        __builtin_amdgcn_s_setprio(0);
        if (ks == 3) {                          // fold chunk's cols into running argmin
            #pragma unroll
            for (int nf = 0; nf < 2; ++nf) {
                int col = ct * 128 + wx * 32 + nf * 16 + (lane & 15);
                float s2 = sumb2[col];          // L1-resident (16 KB)
                #pragma unroll
                for (int mf = 0; mf < 4; ++mf)
                    #pragma unroll
                    for (int r = 0; r < 4; ++r) {
                        float s = s2 - (2.0f * W_SCALE) * acc[mf][nf][r];
                        if (s < bv_[mf][r]) { bv_[mf][r] = s; bi_[mf][r] = col; }
                        acc[mf][nf][r] = 0.0f;
                    }
            }
        }
        __syncthreads();
    }

    // ---- final reduce: 16-lane col groups, then 4 wx-waves via LDS ----
    float* sv = (float*)(lds + 32768);          // [4][64] (B region, post-barrier)
    int*   si = (int*)  (lds + 32768 + 1024);
    #pragma unroll
    for (int mf = 0; mf < 4; ++mf)
        #pragma unroll
        for (int r = 0; r < 4; ++r) {
            float v = bv_[mf][r]; int bi = bi_[mf][r];
            #pragma unroll
            for (int m = 1; m <= 8; m <<= 1) {
                float ov = __shfl_xor(v, m, 64);
                int   oi = __shfl_xor(bi, m, 64);
                if (ov < v || (ov == v && oi < bi)) { v = ov; bi = oi; }
            }
            if ((lane & 15) == 0) {
                int rl = mf * 16 + (lane >> 4) * 4 + r;   // local row 0..63
                sv[wx * 64 + rl] = v;
                si[wx * 64 + rl] = bi;
            }
        }
    __syncthreads();
    if (t < 64) {
        float v = sv[t]; int bi = si[t];
        #pragma unroll
        for (int g = 1; g < 4; ++g) {
            float ov = sv[g * 64 + t]; int oi = si[g * 64 + t];
            if (ov < v) { v = ov; bi = oi; }
        }
        indices[rowBase + t] = bi;
        atomicAdd(&counts[bi], 1);
    }
}

// ---------------- k4: write one-hot encodings directly (0s + the 1) ----------------
__global__ void vq_enc(const int* __restrict__ indices, float2* __restrict__ enc) {
    size_t f = (size_t)blockIdx.x * 256 + threadIdx.x;
    const size_t total = (size_t)N_IN * 2048;
    size_t stride = (size_t)gridDim.x * 256;
    for (; f < total; f += stride) {
        int n = (int)(f >> 11), j = (int)(f & 2047);
        int idx = indices[n];
        float2 v; v.x = 0.0f; v.y = 0.0f;
        if ((idx >> 1) == j) { if (idx & 1) v.y = 1.0f; else v.x = 1.0f; }
        enc[f] = v;
    }
}

// ---------------- k5: gather quantized, straight-through, loss partial ----------------
__global__ void vq_quant(const float* __restrict__ x, const float* __restrict__ w,
                         const int* __restrict__ indices, float* __restrict__ out,
                         float* __restrict__ lossacc) {
    const float4* gx = (const float4*)x;
    const float4* gw = (const float4*)w;
    float* q = out + 1;   // 4B-aligned only -> scalar stores
    size_t tid = (size_t)blockIdx.x * 256 + threadIdx.x;
    size_t stride = (size_t)gridDim.x * 256;
    float s = 0.0f;
    for (size_t f = tid; f < (ND / 4); f += stride) {
        int n = (int)(f >> 6), d4 = (int)(f & 63);
        float4 xv = gx[f];
        float4 ev = gw[(size_t)indices[n] * 64 + d4];
        float dx = ev.x - xv.x, dy = ev.y - xv.y, dz = ev.z - xv.z, dw = ev.w - xv.w;
        s += dx * dx + dy * dy + dz * dz + dw * dw;
        size_t o = (size_t)n * 256 + (size_t)d4 * 4;
        q[o]     = xv.x + dx;
        q[o + 1] = xv.y + dy;
        q[o + 2] = xv.z + dz;
        q[o + 3] = xv.w + dw;
    }
    #pragma unroll
    for (int off = 32; off; off >>= 1) s += __shfl_down(s, off, 64);
    if ((threadIdx.x & 63) == 0) atomicAdd(lossacc, s);
}

// ---------------- k6: finalize loss + perplexity ----------------
__global__ void vq_final(const int* __restrict__ counts, const float* __restrict__ lossacc,
                         float* __restrict__ out) {
    __shared__ float red[4];
    int t = threadIdx.x;
    float e = 0.0f;
    #pragma unroll
    for (int k = 0; k < 16; ++k) {
        float p = (float)counts[t + 256 * k] * (1.0f / 32768.0f);
        e += p * logf(p + 1e-10f);
    }
    #pragma unroll
    for (int off = 32; off; off >>= 1) e += __shfl_down(e, off, 64);
    if ((t & 63) == 0) red[t >> 6] = e;
    __syncthreads();
    if (t == 0) {
        float ent = red[0] + red[1] + red[2] + red[3];
        out[0] = 1.25f * lossacc[0] / 8388608.0f;
        out[OUT_PERP_OFF] = expf(-ent);
    }
}

extern "C" void kernel_launch(void* const* d_in, const int* in_sizes, int n_in,
                              void* d_out, int out_size, void* d_ws, size_t ws_size,
                              hipStream_t stream) {
    const float* x = (const float*)d_in[0];
    const float* w = (const float*)d_in[1];
    float* out = (float*)d_out;
    char* ws = (char*)d_ws;
    float* sumb2   = (float*)(ws + WS_SUMB2);
    int*   counts  = (int*)  (ws + WS_COUNTS);
    float* lossacc = (float*)(ws + WS_LOSS);
    int*   indices = (int*)  (ws + WS_IDX);

    // B' (2 MB) lives at the start of the encodings output region (overwritten by vq_enc later)
    ushort* Bbuf = (ushort*)((char*)d_out + (size_t)OUT_ENC_OFF * 4 + 8);   // 16B aligned

    hipMemsetAsync(ws + WS_COUNTS, 0, 16384 + 4, stream);

    vq_convw<<<1024, 256, 0, stream>>>(w, Bbuf);
    vq_sumb2<<<K_EMB / 4, 256, 0, stream>>>(Bbuf, sumb2);
    vq_gemm_argmin<<<N_IN / 64, 256, 0, stream>>>(x, Bbuf, sumb2, indices, counts);
    vq_enc<<<8192, 256, 0, stream>>>(indices, (float2*)(out + OUT_ENC_OFF));
    vq_quant<<<2048, 256, 0, stream>>>(x, w, indices, out, lossacc);
    vq_final<<<1, 256, 0, stream>>>(counts, lossacc, out);
}